// Round 1
// baseline (19070.462 us; speedup 1.0000x reference)
//
#include <hip/hip_runtime.h>

#define SEQ_T 2048
#define DIN   16
#define HH    80
#define NG    320   // 4*H
#define BT    2     // batches per block
#define NBLK  256   // 256 * BT = 512 = BATCH

__device__ __forceinline__ float rcp_fast(float x) { return __builtin_amdgcn_rcpf(x); }
// stable: x->-inf : exp(-x)->inf, rcp(inf)=0 ; x->+inf : exp(-x)->0 -> 1
__device__ __forceinline__ float sigm(float x)   { return rcp_fast(1.0f + __expf(-x)); }
// tanh(x) = 1 - 2/(1+e^{2x}); saturates correctly at +/-inf via rcp(inf)=0
__device__ __forceinline__ float tanh_f(float x) { return 1.0f - 2.0f * rcp_fast(1.0f + __expf(2.0f * x)); }

__global__ __launch_bounds__(512, 2) void lstm2_fused(
    const float* __restrict__ x,
    const float* __restrict__ W_ih1, const float* __restrict__ W_hh1,
    const float* __restrict__ b_ih1, const float* __restrict__ b_hh1,
    const float* __restrict__ W_ih2, const float* __restrict__ W_hh2,
    const float* __restrict__ b_ih2, const float* __restrict__ b_hh2,
    const float* __restrict__ W_d,   const float* __restrict__ b_d,
    float* __restrict__ out)
{
    // LDS state (~14 KB)
    __shared__ float h1[BT][HH];      // layer-1 hidden (= y1 for current step)
    __shared__ float h2[BT][HH];      // layer-2 hidden
    __shared__ float pL1[BT][NG];     // W_hh1 @ h1 partials
    __shared__ float pI2[BT][NG];     // W_ih2 @ h1 partials
    __shared__ float pH2[BT][NG];     // W_hh2 @ h2 partials
    __shared__ float px [BT][NG];     // W_ih1 @ x_t partials
    __shared__ float bs1[NG];
    __shared__ float bs2[NG];

    const int t  = threadIdx.x;
    const int wv = t >> 6;
    const int b0 = blockIdx.x * BT;

    // ---- stage bias sums, zero h ----
    if (t < NG) { bs1[t] = b_ih1[t] + b_hh1[t]; bs2[t] = b_ih2[t] + b_hh2[t]; }
    if (t < BT*HH)              ((float*)h1)[t]          = 0.0f;
    else if (t < 2*BT*HH)       ((float*)h2)[t - BT*HH]  = 0.0f;

    // ---- persistent weight registers: 2 x 80 floats/thread ----
    float wa[HH], wb[HH];
    {
        const float4 *A, *B;
        if (wv < 5) {                 // threads 0..319: W_hh1 row t  +  W_ih2 row t
            A = (const float4*)(W_hh1 + (size_t)t * HH);
            B = (const float4*)(W_ih2 + (size_t)t * HH);
        } else if (wv < 7) {          // threads 320..447: W_hh2 rows 2i, 2i+1
            const int i = t - 320;
            A = (const float4*)(W_hh2 + (size_t)(2*i)   * HH);
            B = (const float4*)(W_hh2 + (size_t)(2*i+1) * HH);
        } else {                      // threads 448..511: W_hh2 row 256+l + W_ih1 rows 5l..5l+4
            const int l = t - 448;
            A = (const float4*)(W_hh2 + (size_t)(256+l) * HH);
            B = (const float4*)(W_ih1 + (size_t)(5*l)   * DIN);   // 5*16 = 80 contiguous floats
        }
        #pragma unroll
        for (int q = 0; q < HH/4; ++q) {
            float4 av = A[q], bv = B[q];
            wa[4*q+0]=av.x; wa[4*q+1]=av.y; wa[4*q+2]=av.z; wa[4*q+3]=av.w;
            wb[4*q+0]=bv.x; wb[4*q+1]=bv.y; wb[4*q+2]=bv.z; wb[4*q+3]=bv.w;
        }
    }

    // ---- update-role constants (threads 0..319 each own one (layer,unit,batch)) ----
    const bool isUpd = (t < 2*HH*BT);       // 320
    bool isL1 = false; int u = 0, bb = 0;
    const float *pAp = nullptr, *pBp = nullptr, *bsp = nullptr;
    float *hdst = nullptr;
    if (isUpd) {
        int idx = t;
        isL1 = (idx < HH*BT);               // < 160
        if (!isL1) idx -= HH*BT;
        bb = idx / HH; u = idx - bb*HH;
        pAp  = isL1 ? &pL1[bb][0] : &pI2[bb][0];
        pBp  = isL1 ? &px [bb][0] : &pH2[bb][0];
        bsp  = isL1 ? bs1 : bs2;
        hdst = isL1 ? &h1[bb][u] : &h2[bb][u];
    }
    float c_reg = 0.0f;

    __syncthreads();

    // Pipelined: iteration k computes L1 partials for t=k and L2 partials for t=k-1.
    #pragma unroll 1
    for (int k = 0; k <= SEQ_T; ++k) {
        // ================= P phase: register-resident GEMV partials =================
        if (wv < 5) {
            float a00=0.f,a01=0.f,a10=0.f,a11=0.f;
            #pragma unroll
            for (int j = 0; j < HH; ++j) {
                const float v0 = h1[0][j], v1 = h1[1][j];   // LDS broadcast
                a00 += wa[j]*v0; a01 += wa[j]*v1;
                a10 += wb[j]*v0; a11 += wb[j]*v1;
            }
            pL1[0][t]=a00; pL1[1][t]=a01;
            pI2[0][t]=a10; pI2[1][t]=a11;
        } else if (wv < 7) {
            const int r0 = 2*(t-320), r1 = r0+1;
            float a00=0.f,a01=0.f,a10=0.f,a11=0.f;
            #pragma unroll
            for (int j = 0; j < HH; ++j) {
                const float v0 = h2[0][j], v1 = h2[1][j];
                a00 += wa[j]*v0; a01 += wa[j]*v1;
                a10 += wb[j]*v0; a11 += wb[j]*v1;
            }
            pH2[0][r0]=a00; pH2[1][r0]=a01;
            pH2[0][r1]=a10; pH2[1][r1]=a11;
        } else {
            const int l = t - 448, r = 256 + l;
            float a0=0.f, a1=0.f;
            #pragma unroll
            for (int j = 0; j < HH; ++j) {
                a0 += wa[j]*h2[0][j];
                a1 += wa[j]*h2[1][j];
            }
            pH2[0][r]=a0; pH2[1][r]=a1;
            if (k < SEQ_T) {                        // x-projection for timestep k
                #pragma unroll
                for (int b = 0; b < BT; ++b) {
                    const float4* xp = (const float4*)(x + ((size_t)(b0+b)*SEQ_T + (size_t)k)*DIN);
                    float xv[DIN];
                    const float4 q0=xp[0], q1=xp[1], q2=xp[2], q3=xp[3];
                    xv[0]=q0.x; xv[1]=q0.y; xv[2]=q0.z; xv[3]=q0.w;
                    xv[4]=q1.x; xv[5]=q1.y; xv[6]=q1.z; xv[7]=q1.w;
                    xv[8]=q2.x; xv[9]=q2.y; xv[10]=q2.z; xv[11]=q2.w;
                    xv[12]=q3.x; xv[13]=q3.y; xv[14]=q3.z; xv[15]=q3.w;
                    #pragma unroll
                    for (int r5 = 0; r5 < 5; ++r5) {
                        float acc = 0.f;
                        #pragma unroll
                        for (int d = 0; d < DIN; ++d) acc += wb[16*r5+d]*xv[d];
                        px[b][5*l + r5] = acc;
                    }
                }
            }
        }
        __syncthreads();
        // ================= U phase: gate nonlinearities + state update =================
        if (isUpd) {
            const bool active = isL1 ? (k < SEQ_T) : (k >= 1);
            if (active) {
                const float gi = pAp[u       ] + pBp[u       ] + bsp[u       ];
                const float gf = pAp[u +   HH] + pBp[u +   HH] + bsp[u +   HH];
                const float gg = pAp[u + 2*HH] + pBp[u + 2*HH] + bsp[u + 2*HH];
                const float go = pAp[u + 3*HH] + pBp[u + 3*HH] + bsp[u + 3*HH];
                const float iv = sigm(gi), fv = sigm(gf), gv = tanh_f(gg), ov = sigm(go);
                c_reg = fv*c_reg + iv*gv;
                *hdst = ov * tanh_f(c_reg);
            }
        }
        __syncthreads();
    }

    // ---- dense head: out[b] = h2_last[b] . W_d + b_d ----
    if (t < BT) {
        float acc = b_d[0];
        #pragma unroll
        for (int u2 = 0; u2 < HH; ++u2) acc += W_d[u2] * h2[t][u2];
        out[b0 + t] = acc;
    }
}

extern "C" void kernel_launch(void* const* d_in, const int* in_sizes, int n_in,
                              void* d_out, int out_size, void* d_ws, size_t ws_size,
                              hipStream_t stream) {
    const float* x     = (const float*)d_in[0];
    const float* W_ih1 = (const float*)d_in[1];
    const float* W_hh1 = (const float*)d_in[2];
    const float* b_ih1 = (const float*)d_in[3];
    const float* b_hh1 = (const float*)d_in[4];
    const float* W_ih2 = (const float*)d_in[5];
    const float* W_hh2 = (const float*)d_in[6];
    const float* b_ih2 = (const float*)d_in[7];
    const float* b_hh2 = (const float*)d_in[8];
    const float* W_d   = (const float*)d_in[9];
    const float* b_d   = (const float*)d_in[10];

    lstm2_fused<<<NBLK, 512, 0, stream>>>(x, W_ih1, W_hh1, b_ih1, b_hh1,
                                          W_ih2, W_hh2, b_ih2, b_hh2,
                                          W_d, b_d, (float*)d_out);
}